// Round 9
// baseline (454.480 us; speedup 1.0000x reference)
//
#include <hip/hip_runtime.h>
#include <hip/hip_bf16.h>
#include <hip/hip_cooperative_groups.h>

namespace cg = cooperative_groups;

#define V_NODES 100000
#define DIM 128
#define BATCH 16384
#define SAMP 64
#define NEDGE 640000
#define NSAMP (BATCH * SAMP)
#define NB_CHUNK 98          // ceil(V/1024)
#define CSR_BLOCKS 512

// bf16 helpers: raw-bit unpack (exact) and RNE pack
__device__ __forceinline__ float bl(unsigned u) { return __uint_as_float(u << 16); }
__device__ __forceinline__ float bh(unsigned u) { return __uint_as_float(u & 0xffff0000u); }
__device__ __forceinline__ unsigned short f2bf(float x) {
    unsigned u = __float_as_uint(x);
    return (unsigned short)((u + 0x7fffu + ((u >> 16) & 1u)) >> 16);
}

typedef __attribute__((ext_vector_type(8))) short bf16x8;
typedef __attribute__((ext_vector_type(4))) float f32x4;

// ---------- K1 (cooperative): full CSR build in one launch ----------
// phases: zero cnt -> count -> chunk sums -> chunk scan -> offsets/dinv/cursor -> fill
__global__ __launch_bounds__(256, 2) void k_csr(const int* __restrict__ esrc,
        const int* __restrict__ edst, int* __restrict__ cnt, int* __restrict__ bsum,
        int* __restrict__ boff, int* __restrict__ offs, float* __restrict__ dinv,
        int* __restrict__ cursor, int* __restrict__ csr) {
    cg::grid_group grid = cg::this_grid();
    __shared__ int red[4];
    __shared__ int wsum[4];
    int t = threadIdx.x, bid = blockIdx.x;
    int lane = t & 63, wid = t >> 6;
    int gtid = bid * 256 + t;
    int gstride = gridDim.x * 256;

    // Z: zero counters
    for (int i = gtid; i < V_NODES; i += gstride) cnt[i] = 0;
    grid.sync();

    // C: in-degree histogram
    for (int e = gtid; e < NEDGE; e += gstride) atomicAdd(&cnt[edst[e]], 1);
    grid.sync();

    // S1: per-1024-chunk sums (blocks 0..97)
    if (bid < NB_CHUNK) {
        int s = 0;
        int base = bid * 1024;
        for (int i = 0; i < 4; ++i) {
            int idx = base + i * 256 + t;
            if (idx < V_NODES) s += cnt[idx];
        }
        for (int m = 32; m >= 1; m >>= 1) s += __shfl_xor(s, m, 64);
        if (lane == 0) red[wid] = s;
        __syncthreads();
        if (t == 0) bsum[bid] = red[0] + red[1] + red[2] + red[3];
    }
    grid.sync();

    // S2: single-wave shuffle scan of 98 chunk sums (block 0, wave 0)
    if (bid == 0 && t < 64) {
        int i0 = 2 * t, i1 = 2 * t + 1;
        int v0 = (i0 < NB_CHUNK) ? bsum[i0] : 0;
        int v1 = (i1 < NB_CHUNK) ? bsum[i1] : 0;
        int s = v0 + v1;
        int x = s;
        for (int off = 1; off < 64; off <<= 1) {
            int n = __shfl_up(x, off, 64);
            if (t >= off) x += n;
        }
        int excl = x - s;
        if (i0 < NB_CHUNK) boff[i0] = excl;
        if (i1 < NB_CHUNK) boff[i1] = excl + v0;
    }
    grid.sync();

    // S3: exclusive offsets + dinv + cursor init (blocks 0..97)
    if (bid < NB_CHUNK) {
        int base = bid * 1024 + t * 4;
        int c[4];
        for (int j = 0; j < 4; ++j) {
            int idx = base + j;
            c[j] = (idx < V_NODES) ? cnt[idx] : 0;
        }
        int tot = c[0] + c[1] + c[2] + c[3];
        int x = tot;
        for (int off = 1; off < 64; off <<= 1) {
            int n = __shfl_up(x, off, 64);
            if (lane >= off) x += n;
        }
        int lex = x - tot;
        if (lane == 63) wsum[wid] = x;
        __syncthreads();
        int wpre = 0;
        for (int w = 0; w < wid; ++w) wpre += wsum[w];
        int o = boff[bid] + wpre + lex;
        int pre = 0;
        for (int j = 0; j < 4; ++j) {
            int idx = base + j;
            if (idx < V_NODES) {
                int off0 = o + pre;
                offs[idx] = off0;
                cursor[idx] = off0;            // absolute cursor
                dinv[idx] = 1.0f / sqrtf((float)(c[j] + 1));
            }
            pre += c[j];
        }
    }
    grid.sync();

    // F: fill CSR (absolute atomic cursors)
    for (int e = gtid; e < NEDGE; e += gstride) {
        int d = edst[e];
        int pos = atomicAdd(&cursor[d], 1);
        csr[pos] = esrc[e];
    }
}

// ---------- K2: MFMA GEMM  h_bf = bf16(bf16(emb) @ bf16(W)) ----------
#define WTP 136
__global__ __launch_bounds__(256) void k_hgemm(const float* __restrict__ emb,
                      unsigned short* __restrict__ h_bf,
                      const float* __restrict__ W, int V) {
    __shared__ unsigned short At[64][WTP];    // A tile bf16 (also reused for D out)
    __shared__ unsigned short Wt[128][WTP];   // W^T bf16
    int t = threadIdx.x;
    int rowbase = blockIdx.x * 64;
    for (int i = t; i < 128 * 32; i += 256) {
        int k  = i >> 5;
        int n4 = (i & 31) << 2;
        float4 w4 = *(const float4*)(W + k * 128 + n4);
        Wt[n4 + 0][k] = f2bf(w4.x);
        Wt[n4 + 1][k] = f2bf(w4.y);
        Wt[n4 + 2][k] = f2bf(w4.z);
        Wt[n4 + 3][k] = f2bf(w4.w);
    }
    for (int i = t; i < 64 * 32; i += 256) {
        int r  = i >> 5;
        int c4 = (i & 31) << 2;
        int gr = rowbase + r;
        float4 a4 = (gr < V) ? *(const float4*)(emb + (size_t)gr * 128 + c4)
                             : make_float4(0.f, 0.f, 0.f, 0.f);
        ushort4 p;
        p.x = f2bf(a4.x); p.y = f2bf(a4.y); p.z = f2bf(a4.z); p.w = f2bf(a4.w);
        *(ushort4*)&At[r][c4] = p;
    }
    __syncthreads();
    int wid = t >> 6, lane = t & 63;
    int r16  = lane & 15;
    int kgrp = lane >> 4;
    f32x4 acc[8] = {};
    #pragma unroll
    for (int ks = 0; ks < 4; ++ks) {
        bf16x8 a = *(const bf16x8*)&At[wid * 16 + r16][ks * 32 + kgrp * 8];
        #pragma unroll
        for (int n = 0; n < 8; ++n) {
            bf16x8 b = *(const bf16x8*)&Wt[n * 16 + r16][ks * 32 + kgrp * 8];
            acc[n] = __builtin_amdgcn_mfma_f32_16x16x32_bf16(a, b, acc[n], 0, 0, 0);
        }
    }
    __syncthreads();
    #pragma unroll
    for (int n = 0; n < 8; ++n) {
        #pragma unroll
        for (int r = 0; r < 4; ++r) {
            At[wid * 16 + kgrp * 4 + r][n * 16 + r16] = f2bf(acc[n][r]);
        }
    }
    __syncthreads();
    for (int i = t; i < 64 * 16; i += 256) {
        int r  = i >> 4;
        int c8 = (i & 15) << 3;
        int gr = rowbase + r;
        if (gr < V) *(uint4*)(h_bf + (size_t)gr * 128 + c8) = *(const uint4*)&At[r][c8];
    }
}

// ---------- K3: aggregate h, + bias, write bf16 nodes ----------
// one wave per node; neighbor loop UNROLLED x4 -> 4 gathers in flight per wave
// (was serially dependent at VGPR_Count=12; per-wave memory-level parallelism
// is the k_agg limiter, not chip gather rate).
__global__ __launch_bounds__(256) void k_agg(const unsigned short* __restrict__ h_bf,
                     const int* __restrict__ offs, const int* __restrict__ cnt,
                     const int* __restrict__ csr, const float* __restrict__ dinv,
                     const float* __restrict__ bias,
                     unsigned* __restrict__ nodes_h, int V) {
    int wid = threadIdx.x >> 6;
    int lane = threadIdx.x & 63;
    int v = blockIdx.x * 4 + wid;
    if (v >= V) return;
    float dv = dinv[v];
    int beg = offs[v], num = cnt[v];
    int nid = 0; float nw = 0.0f;
    if (lane < num) {
        nid = csr[beg + lane];
        nw = dinv[nid];
    }
    unsigned u0 = ((const unsigned*)(h_bf + (size_t)v * DIM))[lane];
    float wself = dv * dv;
    float2 bv = ((const float2*)bias)[lane];
    float ax = bv.x + wself * bl(u0), ay = bv.y + wself * bh(u0);
    float cx = 0.f, cy = 0.f;   // second accumulator pair
    int n0 = min(num, 64);
    int i = 0;
    for (; i + 4 <= n0; i += 4) {
        int s0 = __shfl(nid, i,     64);
        int s1 = __shfl(nid, i + 1, 64);
        int s2 = __shfl(nid, i + 2, 64);
        int s3 = __shfl(nid, i + 3, 64);
        float w0 = dv * __shfl(nw, i,     64);
        float w1 = dv * __shfl(nw, i + 1, 64);
        float w2 = dv * __shfl(nw, i + 2, 64);
        float w3 = dv * __shfl(nw, i + 3, 64);
        unsigned e0 = ((const unsigned*)(h_bf + (size_t)s0 * DIM))[lane];
        unsigned e1 = ((const unsigned*)(h_bf + (size_t)s1 * DIM))[lane];
        unsigned e2 = ((const unsigned*)(h_bf + (size_t)s2 * DIM))[lane];
        unsigned e3 = ((const unsigned*)(h_bf + (size_t)s3 * DIM))[lane];
        ax += w0 * bl(e0); ay += w0 * bh(e0);
        cx += w1 * bl(e1); cy += w1 * bh(e1);
        ax += w2 * bl(e2); ay += w2 * bh(e2);
        cx += w3 * bl(e3); cy += w3 * bh(e3);
    }
    for (; i < n0; ++i) {
        int s = __shfl(nid, i, 64);
        float w = dv * __shfl(nw, i, 64);
        unsigned u = ((const unsigned*)(h_bf + (size_t)s * DIM))[lane];
        ax += w * bl(u); ay += w * bh(u);
    }
    for (int k = 64; k < num; ++k) {        // cold fallback (deg>64 ~ impossible)
        int s = csr[beg + k];
        float w = dv * dinv[s];
        unsigned u = ((const unsigned*)(h_bf + (size_t)s * DIM))[lane];
        ax += w * bl(u); ay += w * bh(u);
    }
    ax += cx; ay += cy;
    nodes_h[(size_t)v * (DIM / 2) + lane] =
        (unsigned)f2bf(ax) | ((unsigned)f2bf(ay) << 16);
}

// ---------- K4: scores[b,s] = dot(nodes[items[b]], nodes[samples[b,s]]) ----------
__global__ __launch_bounds__(256) void k_score(const unsigned short* __restrict__ nodes_h,
                      const int* __restrict__ items, const int* __restrict__ samples,
                      float* __restrict__ out) {
    int b = blockIdx.x;
    int t = threadIdx.x;
    int q = t & 3;
    int sidx = t >> 2;
    int item = items[b];
    const uint4* irow = (const uint4*)(nodes_h + (size_t)item * DIM) + q * 4;
    uint4 a[4];
    #pragma unroll
    for (int c = 0; c < 4; ++c) a[c] = irow[c];

    int j = samples[b * SAMP + sidx];
    const uint4* srow = (const uint4*)(nodes_h + (size_t)j * DIM) + q * 4;
    uint4 s4[4];
    #pragma unroll
    for (int c = 0; c < 4; ++c) s4[c] = srow[c];

    float p = 0.f;
    #pragma unroll
    for (int c = 0; c < 4; ++c) {
        uint4 av = a[c], sv = s4[c];
        p += bl(av.x) * bl(sv.x) + bh(av.x) * bh(sv.x);
        p += bl(av.y) * bl(sv.y) + bh(av.y) * bh(sv.y);
        p += bl(av.z) * bl(sv.z) + bh(av.z) * bh(sv.z);
        p += bl(av.w) * bl(sv.w) + bh(av.w) * bh(sv.w);
    }
    p += __shfl_xor(p, 1, 64);
    p += __shfl_xor(p, 2, 64);
    if (q == 0) out[b * SAMP + sidx] = p;
}

extern "C" void kernel_launch(void* const* d_in, const int* in_sizes, int n_in,
                              void* d_out, int out_size, void* d_ws, size_t ws_size,
                              hipStream_t stream) {
    const int*   items   = (const int*)d_in[0];
    const int*   samples = (const int*)d_in[1];
    const int*   edges   = (const int*)d_in[2];
    const float* emb     = (const float*)d_in[3];
    const float* W       = (const float*)d_in[4];
    const float* bias    = (const float*)d_in[5];
    float* out = (float*)d_out;

    char* ws = (char*)d_ws;
    int*   cnt    = (int*)(ws + 0);                        // V ints (400 KB)
    int*   cursor = (int*)(ws + (512 << 10));              // V ints
    float* dinv   = (float*)(ws + (1 << 20));              // V floats
    int*   offs   = (int*)(ws + 3 * (512 << 10));          // V ints
    int*   bsum   = (int*)(ws + (2 << 20));                // 98 ints
    int*   boff   = (int*)(ws + (2 << 20) + (4 << 10));    // 98 ints
    int*   csr    = (int*)(ws + (4 << 20));                // E ints (2.56 MB)
    unsigned short* h_bf    = (unsigned short*)(ws + (8 << 20));   // V*DIM bf16 (25.6 MB)
    unsigned*       nodes_h = (unsigned*)(ws + (34 << 20));        // V*DIM bf16 (25.6 MB)

    const int* esrc = edges;
    const int* edst = edges + NEDGE;

    // CSR build: one cooperative launch (zero+count+scan+offs+fill)
    {
        void* args[] = { (void*)&esrc, (void*)&edst, (void*)&cnt, (void*)&bsum,
                         (void*)&boff, (void*)&offs, (void*)&dinv, (void*)&cursor,
                         (void*)&csr };
        hipLaunchCooperativeKernel((void*)k_csr, dim3(CSR_BLOCKS), dim3(256),
                                   args, 0, stream);
    }
    // GCN: MFMA GEMM first (reference order), then aggregate
    k_hgemm<<<(V_NODES + 63) / 64, 256, 0, stream>>>(emb, h_bf, W, V_NODES);
    k_agg  <<<(V_NODES + 3) / 4, 256, 0, stream>>>(h_bf, offs, cnt, csr, dinv, bias, nodes_h, V_NODES);
    // scoring
    k_score<<<BATCH, 256, 0, stream>>>((const unsigned short*)nodes_h, items, samples, out);
}

// Round 10
// 208.170 us; speedup vs baseline: 2.1832x; 2.1832x over previous
//
#include <hip/hip_runtime.h>
#include <hip/hip_bf16.h>

#define V_NODES 100000
#define DIM 128
#define BATCH 16384
#define SAMP 64
#define NEDGE 640000
#define NSAMP (BATCH * SAMP)

// bf16 helpers: raw-bit unpack (exact) and RNE pack
__device__ __forceinline__ float bl(unsigned u) { return __uint_as_float(u << 16); }
__device__ __forceinline__ float bh(unsigned u) { return __uint_as_float(u & 0xffff0000u); }
__device__ __forceinline__ unsigned short f2bf(float x) {
    unsigned u = __float_as_uint(x);
    return (unsigned short)((u + 0x7fffu + ((u >> 16) & 1u)) >> 16);
}

typedef __attribute__((ext_vector_type(8))) short bf16x8;
typedef __attribute__((ext_vector_type(4))) float f32x4;

// ---------- K1: histogram of edge destinations (in-degree) ----------
__global__ void k_count(const int* __restrict__ key, int* __restrict__ cnt, int E) {
    int e = blockIdx.x * blockDim.x + threadIdx.x;
    if (e < E) atomicAdd(&cnt[key[e]], 1);
}

// ---------- K2a: per-1024-chunk sums ----------
__global__ void k_bsum(const int* __restrict__ cnt, int* __restrict__ bsum, int V) {
    __shared__ int red[4];
    int b = blockIdx.x, t = threadIdx.x;
    int s = 0;
    int base = b * 1024;
    for (int i = 0; i < 4; ++i) {
        int idx = base + i * 256 + t;
        if (idx < V) s += cnt[idx];
    }
    for (int m = 32; m >= 1; m >>= 1) s += __shfl_xor(s, m, 64);
    int lane = t & 63, wid = t >> 6;
    if (lane == 0) red[wid] = s;
    __syncthreads();
    if (t == 0) bsum[b] = red[0] + red[1] + red[2] + red[3];
}

// ---------- K2b: single-wave shuffle scan of chunk sums ----------
__global__ void k_bscan(const int* __restrict__ bsum, int* __restrict__ boff, int nb) {
    int l = threadIdx.x;            // 64 threads, 2 elements per lane
    int i0 = 2 * l, i1 = 2 * l + 1;
    int v0 = (i0 < nb) ? bsum[i0] : 0;
    int v1 = (i1 < nb) ? bsum[i1] : 0;
    int s = v0 + v1;
    int x = s;
    for (int off = 1; off < 64; off <<= 1) {
        int n = __shfl_up(x, off, 64);
        if (l >= off) x += n;
    }
    int excl = x - s;
    if (i0 < nb) boff[i0] = excl;
    if (i1 < nb) boff[i1] = excl + v0;
}

// ---------- K2c: exclusive CSR offsets + dinv = 1/sqrt(deg+1) ----------
__global__ void k_offs(const int* __restrict__ cnt, const int* __restrict__ boff,
                       int* __restrict__ offs, float* __restrict__ dinv, int V) {
    __shared__ int wsum[4];
    int b = blockIdx.x, t = threadIdx.x;
    int lane = t & 63, wid = t >> 6;
    int base = b * 1024 + t * 4;
    int c[4];
    for (int j = 0; j < 4; ++j) {
        int idx = base + j;
        c[j] = (idx < V) ? cnt[idx] : 0;
    }
    int tot = c[0] + c[1] + c[2] + c[3];
    int x = tot;
    for (int off = 1; off < 64; off <<= 1) {
        int n = __shfl_up(x, off, 64);
        if (lane >= off) x += n;
    }
    int lex = x - tot;
    if (lane == 63) wsum[wid] = x;
    __syncthreads();
    int wpre = 0;
    for (int w = 0; w < wid; ++w) wpre += wsum[w];
    int o = boff[b] + wpre + lex;
    int pre = 0;
    for (int j = 0; j < 4; ++j) {
        int idx = base + j;
        if (idx < V) {
            offs[idx] = o + pre;
            dinv[idx] = 1.0f / sqrtf((float)(c[j] + 1));
        }
        pre += c[j];
    }
}

// ---------- K3: fill edge CSR (int atomic cursors) ----------
__global__ void k_fill(const int* __restrict__ src, const int* __restrict__ dst,
                       const int* __restrict__ offs, int* __restrict__ cursor,
                       int* __restrict__ csr, int E) {
    int e = blockIdx.x * blockDim.x + threadIdx.x;
    if (e < E) {
        int d = dst[e];
        int pos = atomicAdd(&cursor[d], 1);
        csr[offs[d] + pos] = src[e];
    }
}

// ---------- K4: MFMA GEMM  h_bf = bf16(bf16(emb) @ bf16(W)) ----------
#define WTP 136
__global__ __launch_bounds__(256) void k_hgemm(const float* __restrict__ emb,
                      unsigned short* __restrict__ h_bf,
                      const float* __restrict__ W, int V) {
    __shared__ unsigned short At[64][WTP];    // A tile bf16 (also reused for D out)
    __shared__ unsigned short Wt[128][WTP];   // W^T bf16
    int t = threadIdx.x;
    int rowbase = blockIdx.x * 64;
    for (int i = t; i < 128 * 32; i += 256) {
        int k  = i >> 5;
        int n4 = (i & 31) << 2;
        float4 w4 = *(const float4*)(W + k * 128 + n4);
        Wt[n4 + 0][k] = f2bf(w4.x);
        Wt[n4 + 1][k] = f2bf(w4.y);
        Wt[n4 + 2][k] = f2bf(w4.z);
        Wt[n4 + 3][k] = f2bf(w4.w);
    }
    for (int i = t; i < 64 * 32; i += 256) {
        int r  = i >> 5;
        int c4 = (i & 31) << 2;
        int gr = rowbase + r;
        float4 a4 = (gr < V) ? *(const float4*)(emb + (size_t)gr * 128 + c4)
                             : make_float4(0.f, 0.f, 0.f, 0.f);
        ushort4 p;
        p.x = f2bf(a4.x); p.y = f2bf(a4.y); p.z = f2bf(a4.z); p.w = f2bf(a4.w);
        *(ushort4*)&At[r][c4] = p;
    }
    __syncthreads();
    int wid = t >> 6, lane = t & 63;
    int r16  = lane & 15;
    int kgrp = lane >> 4;
    f32x4 acc[8] = {};
    #pragma unroll
    for (int ks = 0; ks < 4; ++ks) {
        bf16x8 a = *(const bf16x8*)&At[wid * 16 + r16][ks * 32 + kgrp * 8];
        #pragma unroll
        for (int n = 0; n < 8; ++n) {
            bf16x8 b = *(const bf16x8*)&Wt[n * 16 + r16][ks * 32 + kgrp * 8];
            acc[n] = __builtin_amdgcn_mfma_f32_16x16x32_bf16(a, b, acc[n], 0, 0, 0);
        }
    }
    __syncthreads();
    #pragma unroll
    for (int n = 0; n < 8; ++n) {
        #pragma unroll
        for (int r = 0; r < 4; ++r) {
            At[wid * 16 + kgrp * 4 + r][n * 16 + r16] = f2bf(acc[n][r]);
        }
    }
    __syncthreads();
    for (int i = t; i < 64 * 16; i += 256) {
        int r  = i >> 4;
        int c8 = (i & 15) << 3;
        int gr = rowbase + r;
        if (gr < V) *(uint4*)(h_bf + (size_t)gr * 128 + c8) = *(const uint4*)&At[r][c8];
    }
}

// ---------- K5: aggregate h, + bias, write bf16 nodes ----------
// one wave per node; neighbor loop unrolled x4 -> 4 independent gathers in flight.
__global__ __launch_bounds__(256) void k_agg(const unsigned short* __restrict__ h_bf,
                     const int* __restrict__ offs, const int* __restrict__ cnt,
                     const int* __restrict__ csr, const float* __restrict__ dinv,
                     const float* __restrict__ bias,
                     unsigned* __restrict__ nodes_h, int V) {
    int wid = threadIdx.x >> 6;
    int lane = threadIdx.x & 63;
    int v = blockIdx.x * 4 + wid;
    if (v >= V) return;
    float dv = dinv[v];
    int beg = offs[v], num = cnt[v];
    int nid = 0; float nw = 0.0f;
    if (lane < num) {
        nid = csr[beg + lane];
        nw = dinv[nid];
    }
    unsigned u0 = ((const unsigned*)(h_bf + (size_t)v * DIM))[lane];
    float wself = dv * dv;
    float2 bv = ((const float2*)bias)[lane];
    float ax = bv.x + wself * bl(u0), ay = bv.y + wself * bh(u0);
    float cx = 0.f, cy = 0.f;
    int n0 = min(num, 64);
    int i = 0;
    for (; i + 4 <= n0; i += 4) {
        int s0 = __shfl(nid, i,     64);
        int s1 = __shfl(nid, i + 1, 64);
        int s2 = __shfl(nid, i + 2, 64);
        int s3 = __shfl(nid, i + 3, 64);
        float w0 = dv * __shfl(nw, i,     64);
        float w1 = dv * __shfl(nw, i + 1, 64);
        float w2 = dv * __shfl(nw, i + 2, 64);
        float w3 = dv * __shfl(nw, i + 3, 64);
        unsigned e0 = ((const unsigned*)(h_bf + (size_t)s0 * DIM))[lane];
        unsigned e1 = ((const unsigned*)(h_bf + (size_t)s1 * DIM))[lane];
        unsigned e2 = ((const unsigned*)(h_bf + (size_t)s2 * DIM))[lane];
        unsigned e3 = ((const unsigned*)(h_bf + (size_t)s3 * DIM))[lane];
        ax += w0 * bl(e0); ay += w0 * bh(e0);
        cx += w1 * bl(e1); cy += w1 * bh(e1);
        ax += w2 * bl(e2); ay += w2 * bh(e2);
        cx += w3 * bl(e3); cy += w3 * bh(e3);
    }
    for (; i < n0; ++i) {
        int s = __shfl(nid, i, 64);
        float w = dv * __shfl(nw, i, 64);
        unsigned u = ((const unsigned*)(h_bf + (size_t)s * DIM))[lane];
        ax += w * bl(u); ay += w * bh(u);
    }
    for (int k = 64; k < num; ++k) {        // cold fallback (deg>64 ~ impossible)
        int s = csr[beg + k];
        float w = dv * dinv[s];
        unsigned u = ((const unsigned*)(h_bf + (size_t)s * DIM))[lane];
        ax += w * bl(u); ay += w * bh(u);
    }
    ax += cx; ay += cy;
    nodes_h[(size_t)v * (DIM / 2) + lane] =
        (unsigned)f2bf(ax) | ((unsigned)f2bf(ay) << 16);
}

// ---------- K6: scores[b,s] = dot(nodes[items[b]], nodes[samples[b,s]]) ----------
// 128-thread block per item; 2 threads per sample (each owns 64 dims = 8 uint4
// loads in flight -> 2x the per-wave miss parallelism of the 4-thread variant).
__global__ __launch_bounds__(128) void k_score(const unsigned short* __restrict__ nodes_h,
                      const int* __restrict__ items, const int* __restrict__ samples,
                      float* __restrict__ out) {
    int b = blockIdx.x;
    int t = threadIdx.x;
    int q = t & 1;       // half 0/1 (64 dims each)
    int sidx = t >> 1;   // sample 0..63
    int item = items[b];
    const uint4* irow = (const uint4*)(nodes_h + (size_t)item * DIM) + q * 8;
    uint4 a[8];
    #pragma unroll
    for (int c = 0; c < 8; ++c) a[c] = irow[c];    // L1-hot after first wave

    int j = samples[b * SAMP + sidx];
    const uint4* srow = (const uint4*)(nodes_h + (size_t)j * DIM) + q * 8;
    uint4 s4[8];
    #pragma unroll
    for (int c = 0; c < 8; ++c) s4[c] = srow[c];   // 8 independent 16B loads in flight

    float p = 0.f;
    #pragma unroll
    for (int c = 0; c < 8; ++c) {
        uint4 av = a[c], sv = s4[c];
        p += bl(av.x) * bl(sv.x) + bh(av.x) * bh(sv.x);
        p += bl(av.y) * bl(sv.y) + bh(av.y) * bh(sv.y);
        p += bl(av.z) * bl(sv.z) + bh(av.z) * bh(sv.z);
        p += bl(av.w) * bl(sv.w) + bh(av.w) * bh(sv.w);
    }
    p += __shfl_xor(p, 1, 64);
    if (q == 0) out[b * SAMP + sidx] = p;
}

extern "C" void kernel_launch(void* const* d_in, const int* in_sizes, int n_in,
                              void* d_out, int out_size, void* d_ws, size_t ws_size,
                              hipStream_t stream) {
    const int*   items   = (const int*)d_in[0];
    const int*   samples = (const int*)d_in[1];
    const int*   edges   = (const int*)d_in[2];
    const float* emb     = (const float*)d_in[3];
    const float* W       = (const float*)d_in[4];
    const float* bias    = (const float*)d_in[5];
    float* out = (float*)d_out;

    char* ws = (char*)d_ws;
    int*   cnt    = (int*)(ws + 0);                        // V ints (400 KB)
    int*   cursor = (int*)(ws + (512 << 10));              // V ints
    float* dinv   = (float*)(ws + (1 << 20));              // V floats
    int*   offs   = (int*)(ws + 3 * (512 << 10));          // V ints
    int*   bsum   = (int*)(ws + (2 << 20));                // 98 ints
    int*   boff   = (int*)(ws + (2 << 20) + (4 << 10));    // 98 ints
    int*   csr    = (int*)(ws + (4 << 20));                // E ints (2.56 MB)
    unsigned short* h_bf    = (unsigned short*)(ws + (8 << 20));   // V*DIM bf16 (25.6 MB)
    unsigned*       nodes_h = (unsigned*)(ws + (34 << 20));        // V*DIM bf16 (25.6 MB)

    const int* esrc = edges;
    const int* edst = edges + NEDGE;

    hipMemsetAsync(ws, 0, (1 << 20), stream);   // zero cnt + cursor

    int nb = (V_NODES + 1023) / 1024;   // 98
    // edge CSR (by dst) — separate kernels (cooperative fusion regressed 10x, R9)
    k_count<<<(NEDGE + 255) / 256, 256, 0, stream>>>(edst, cnt, NEDGE);
    k_bsum <<<nb, 256, 0, stream>>>(cnt, bsum, V_NODES);
    k_bscan<<<1, 64, 0, stream>>>(bsum, boff, nb);
    k_offs <<<nb, 256, 0, stream>>>(cnt, boff, offs, dinv, V_NODES);
    k_fill <<<(NEDGE + 255) / 256, 256, 0, stream>>>(esrc, edst, offs, cursor, csr, NEDGE);
    // GCN: MFMA GEMM first (reference order), then aggregate
    k_hgemm<<<(V_NODES + 63) / 64, 256, 0, stream>>>(emb, h_bf, W, V_NODES);
    k_agg  <<<(V_NODES + 3) / 4, 256, 0, stream>>>(h_bf, offs, cnt, csr, dinv, bias, nodes_h, V_NODES);
    // scoring
    k_score<<<BATCH, 128, 0, stream>>>((const unsigned short*)nodes_h, items, samples, out);
}